// Round 5
// baseline (176.214 us; speedup 1.0000x reference)
//
#include <hip/hip_runtime.h>

#define BB 2
#define NN 768
#define FIN 10
#define NBLK 288

// workspace layout (float offsets)
#define WPQ_OFF 0                           // 128*128
#define S1P_OFF 16384                       // B*24*128
#define S2P_OFF (S1P_OFF + BB*24*128)       // B*24*128
#define CTR_OFF (S2P_OFF + BB*24*128)       // 24 uints (3 barriers x 8)
#define H1_OFF  32768                       // B*128*768
#define H2_OFF  (H1_OFF + BB*128*NN)
#define PP_OFF  (H2_OFF + BB*128*NN)        // B*64*768
#define QQ_OFF  (PP_OFF + BB*64*NN)

struct SM_L0 {
    float xt[FIN][36];
    float wl[FIN][128];
    float mu[FIN];
    float offs[128];
    float wred[4][FIN];
    float cred[128][9];
};
struct SM_L12 {
    float hl[128][36];
    float wl[64][132];
    float mul[128];
    float offp[4][64];
    float offs[64];
    float off2[64];
    float bp[4][64];
    float bias[64];
    float cred[64][9];
};
struct SM_WPQ {
    float w2l[64][132];
    float sl[16][68];
};
struct SM_FIN {
    float pl[64][68];
    float ql[64][68];
    float wv[64];
    float sb;
};
union alignas(16) SMem { SM_L0 l0; SM_L12 l12; SM_WPQ w; SM_FIN f; };

// device-wide barrier (agent/device scope — sufficient per G16).
// Each barrier instance: ctr at sync[k*8], flag at sync[k*8+4].
__device__ __forceinline__ void gbar(unsigned* sync, int which)
{
    __syncthreads();
    if (threadIdx.x == 0) {
        __threadfence();                                   // release prior writes
        unsigned pos = atomicAdd(&sync[which * 8], 1u);    // device-scope RMW
        if (pos == (unsigned)(NBLK - 1)) {
            __hip_atomic_store(&sync[which * 8 + 4], 1u, __ATOMIC_RELEASE,
                               __HIP_MEMORY_SCOPE_AGENT);
        } else {
            while (__hip_atomic_load(&sync[which * 8 + 4], __ATOMIC_ACQUIRE,
                                     __HIP_MEMORY_SCOPE_AGENT) == 0u)
                __builtin_amdgcn_s_sleep(2);
        }
        __threadfence();                                   // acquire for plain loads
    }
    __syncthreads();
}

__global__ __launch_bounds__(256) void k_mega(
    const float* __restrict__ x,
    const float* __restrict__ w1_0, const float* __restrict__ b1_0,
    const float* __restrict__ w2_0, const float* __restrict__ b2_0,
    const float* __restrict__ w1_1, const float* __restrict__ b1_1,
    const float* __restrict__ w2_1, const float* __restrict__ b2_1,
    const float* __restrict__ w1_2, const float* __restrict__ b1_2,
    const float* __restrict__ w2_2, const float* __restrict__ b2_2,
    const float* __restrict__ sw0, const float* __restrict__ sb0,
    const float* __restrict__ sw1, const float* __restrict__ sb1,
    float* ws, float* __restrict__ out)
{
    __shared__ SMem sm;
    const int blk = blockIdx.x, tid = threadIdx.x;

    float* wpq = ws + WPQ_OFF;
    float* s1p = ws + S1P_OFF;
    float* s2p = ws + S2P_OFF;
    float* h1  = ws + H1_OFF;
    float* h2  = ws + H2_OFF;
    float* pp  = ws + PP_OFF;
    float* qq  = ws + QQ_OFF;
    unsigned* sync = (unsigned*)(ws + CTR_OFF);

    // ================= PHASE 1 =================
    if (blk < 48) {
        // layer0: b in {0,1}, 24 n-tiles of 32; out h1[128o][32n], colsum partial -> s1p
        const int b = blk / 24, nt = blk % 24, n0 = nt * 32;
        for (int idx = tid; idx < FIN * 32; idx += 256) {
            int n = idx / FIN, c = idx % FIN;
            sm.l0.xt[c][n] = x[(b * NN + n0 + n) * FIN + c];
        }
        for (int idx = tid; idx < FIN * 128; idx += 256) {
            int o = idx / FIN, c = idx % FIN;
            sm.l0.wl[c][o] = w1_0[o * FIN + c] + w2_0[o * FIN + c];
        }
        // x-mean (redundant per block; x is 30KB, L2-hot)
        float part[FIN];
#pragma unroll
        for (int c = 0; c < FIN; ++c) part[c] = 0.f;
        for (int n = tid; n < NN; n += 256) {
            const float* xp = x + (b * NN + n) * FIN;
#pragma unroll
            for (int c = 0; c < FIN; ++c) part[c] += xp[c];
        }
#pragma unroll
        for (int off = 32; off > 0; off >>= 1) {
#pragma unroll
            for (int c = 0; c < FIN; ++c) part[c] += __shfl_down(part[c], off);
        }
        if ((tid & 63) == 0) {
#pragma unroll
            for (int c = 0; c < FIN; ++c) sm.l0.wred[tid >> 6][c] = part[c];
        }
        __syncthreads();
        if (tid < FIN) {
            float s = sm.l0.wred[0][tid] + sm.l0.wred[1][tid]
                    + sm.l0.wred[2][tid] + sm.l0.wred[3][tid];
            sm.l0.mu[tid] = s * (1.f / (float)NN);
        }
        __syncthreads();
        if (tid < 128) {
            float o = b1_0[tid] + b2_0[tid];
#pragma unroll
            for (int c = 0; c < FIN; ++c) o -= w2_0[tid * FIN + c] * sm.l0.mu[c];
            sm.l0.offs[tid] = o;
        }
        __syncthreads();
        const int tx = tid & 7, ty = tid >> 3;     // tx: n/4, ty: 4 o rows each
        float4 acc[4];
#pragma unroll
        for (int a = 0; a < 4; ++a) {
            float o = sm.l0.offs[ty * 4 + a];
            acc[a] = make_float4(o, o, o, o);
        }
#pragma unroll
        for (int c = 0; c < FIN; ++c) {
            float4 xv = *(const float4*)&sm.l0.xt[c][tx * 4];
#pragma unroll
            for (int a = 0; a < 4; ++a) {
                float w = sm.l0.wl[c][ty * 4 + a];
                acc[a].x += w * xv.x; acc[a].y += w * xv.y;
                acc[a].z += w * xv.z; acc[a].w += w * xv.w;
            }
        }
#pragma unroll
        for (int a = 0; a < 4; ++a) {
            int o = ty * 4 + a;
            float4 r = acc[a];
            r.x = fmaxf(r.x, 0.f); r.y = fmaxf(r.y, 0.f);
            r.z = fmaxf(r.z, 0.f); r.w = fmaxf(r.w, 0.f);
            *(float4*)&h1[((size_t)(b * 128 + o)) * NN + n0 + tx * 4] = r;
            sm.l0.cred[o][tx] = r.x + r.y + r.z + r.w;
        }
        __syncthreads();
        if (tid < 128) {
            float s = 0.f;
#pragma unroll
            for (int t = 0; t < 8; ++t) s += sm.l0.cred[tid][t];
            s1p[(b * 24 + nt) * 128 + tid] = s;
        }
    } else if (blk >= 280) {
        // Wpq[o][c] = sum_k S[o][k]*(w1_2[k][c]+w2_2[k][c]); 8 blocks x 16 rows
        const int o0 = (blk - 280) * 16;
        for (int idx = tid; idx < 2048; idx += 256) {
            int k = idx >> 5, c4 = (idx & 31) * 4;
            float4 a = *(const float4*)&w1_2[k * 128 + c4];
            float4 b = *(const float4*)&w2_2[k * 128 + c4];
            float4 r = {a.x + b.x, a.y + b.y, a.z + b.z, a.w + b.w};
            *(float4*)&sm.w.w2l[k][c4] = r;
        }
        for (int idx = tid; idx < 16 * 64; idx += 256) {
            int o = idx >> 6, k = idx & 63;
            int oo = o0 + o;
            sm.w.sl[o][k] = (oo < 64) ? sw0[oo * 128 + k] : sw0[(oo - 64) * 128 + 64 + k];
        }
        __syncthreads();
        const int tx = tid & 31, ty = tid >> 5;   // 2 o rows each
        float4 a0 = {0, 0, 0, 0}, a1 = {0, 0, 0, 0};
        for (int k = 0; k < 64; ++k) {
            float4 wv = *(const float4*)&sm.w.w2l[k][tx * 4];
            float s0 = sm.w.sl[ty * 2][k], s1v = sm.w.sl[ty * 2 + 1][k];
            a0.x += s0 * wv.x; a0.y += s0 * wv.y; a0.z += s0 * wv.z; a0.w += s0 * wv.w;
            a1.x += s1v * wv.x; a1.y += s1v * wv.y; a1.z += s1v * wv.z; a1.w += s1v * wv.w;
        }
        *(float4*)&wpq[(o0 + ty * 2) * 128 + tx * 4] = a0;
        *(float4*)&wpq[(o0 + ty * 2 + 1) * 128 + tx * 4] = a1;
    }
    gbar(sync, 0);

    // ================= PHASE 2: layer1 =================
    if (blk < 96) {
        const int b = blk & 1, z = (blk >> 1) & 1, nt = blk >> 2;
        const int n0 = nt * 32, o0 = z * 64;
        if (tid < 128) {
            float s = 0.f;
#pragma unroll
            for (int k = 0; k < 24; ++k) s += s1p[(b * 24 + k) * 128 + tid];
            sm.l12.mul[tid] = s * (1.f / (float)NN);
        }
        for (int idx = tid; idx < 1024; idx += 256) {
            int c = idx >> 3, n4 = (idx & 7) * 4;
            *(float4*)&sm.l12.hl[c][n4] = *(const float4*)&h1[((size_t)(b * 128 + c)) * NN + n0 + n4];
        }
        for (int idx = tid; idx < 2048; idx += 256) {
            int o = idx >> 5, c4 = (idx & 31) * 4;
            float4 a = *(const float4*)&w1_1[(o0 + o) * 128 + c4];
            float4 bb = *(const float4*)&w2_1[(o0 + o) * 128 + c4];
            float4 r = {a.x + bb.x, a.y + bb.y, a.z + bb.z, a.w + bb.w};
            *(float4*)&sm.l12.wl[o][c4] = r;
        }
        __syncthreads();
        {
            int o = tid & 63, p = tid >> 6;
            const float* w2r = w2_1 + (o0 + o) * 128 + p * 32;
            const float* mr = sm.l12.mul + p * 32;
            float s = 0.f;
#pragma unroll
            for (int i = 0; i < 32; ++i) s += w2r[i] * mr[i];
            sm.l12.offp[p][o] = s;
        }
        __syncthreads();
        if (tid < 64)
            sm.l12.offs[tid] = b1_1[o0 + tid] + b2_1[o0 + tid]
                             - sm.l12.offp[0][tid] - sm.l12.offp[1][tid]
                             - sm.l12.offp[2][tid] - sm.l12.offp[3][tid];
        __syncthreads();
        const int tx = tid & 7, ty = tid >> 3;     // 2 o rows, 4 n each
        float4 a0 = {0, 0, 0, 0}, a1 = {0, 0, 0, 0};
        for (int c = 0; c < 128; ++c) {
            float4 hv = *(const float4*)&sm.l12.hl[c][tx * 4];
            float w0 = sm.l12.wl[ty * 2][c], w1v = sm.l12.wl[ty * 2 + 1][c];
            a0.x += w0 * hv.x; a0.y += w0 * hv.y; a0.z += w0 * hv.z; a0.w += w0 * hv.w;
            a1.x += w1v * hv.x; a1.y += w1v * hv.y; a1.z += w1v * hv.z; a1.w += w1v * hv.w;
        }
#pragma unroll
        for (int a = 0; a < 2; ++a) {
            int o = ty * 2 + a;
            float off = sm.l12.offs[o];
            float4 r = a ? a1 : a0;
            r.x = fmaxf(r.x + off, 0.f); r.y = fmaxf(r.y + off, 0.f);
            r.z = fmaxf(r.z + off, 0.f); r.w = fmaxf(r.w + off, 0.f);
            *(float4*)&h2[((size_t)(b * 128 + o0 + o)) * NN + n0 + tx * 4] = r;
            sm.l12.cred[o][tx] = r.x + r.y + r.z + r.w;
        }
        __syncthreads();
        if (tid < 64) {
            float s = 0.f;
#pragma unroll
            for (int t = 0; t < 8; ++t) s += sm.l12.cred[tid][t];
            s2p[(b * 24 + nt) * 128 + o0 + tid] = s;
        }
    }
    gbar(sync, 1);

    // ================= PHASE 3: pp/qq = Wpq @ h2 + bias =================
    if (blk < 96) {
        const int b = blk & 1, z = (blk >> 1) & 1, nt = blk >> 2;
        const int n0 = nt * 32, o0 = z * 64;
        if (tid < 128) {
            float s = 0.f;
#pragma unroll
            for (int k = 0; k < 24; ++k) s += s2p[(b * 24 + k) * 128 + tid];
            sm.l12.mul[tid] = s * (1.f / (float)NN);
        }
        for (int idx = tid; idx < 1024; idx += 256) {
            int c = idx >> 3, n4 = (idx & 7) * 4;
            *(float4*)&sm.l12.hl[c][n4] = *(const float4*)&h2[((size_t)(b * 128 + c)) * NN + n0 + n4];
        }
        for (int idx = tid; idx < 2048; idx += 256) {
            int o = idx >> 5, c4 = (idx & 31) * 4;
            *(float4*)&sm.l12.wl[o][c4] = *(const float4*)&wpq[(o0 + o) * 128 + c4];
        }
        __syncthreads();
        {   // off2[k] = b1_2+b2_2 - w2_2 @ mul  (u-channel offsets)
            int k = tid & 63, p = tid >> 6;
            const float* w2r = w2_2 + k * 128 + p * 32;
            const float* mr = sm.l12.mul + p * 32;
            float s = 0.f;
#pragma unroll
            for (int i = 0; i < 32; ++i) s += w2r[i] * mr[i];
            sm.l12.offp[p][k] = s;
        }
        __syncthreads();
        if (tid < 64)
            sm.l12.off2[tid] = b1_2[tid] + b2_2[tid]
                             - sm.l12.offp[0][tid] - sm.l12.offp[1][tid]
                             - sm.l12.offp[2][tid] - sm.l12.offp[3][tid];
        __syncthreads();
        {   // bias[o] = S[o] @ off2 (+ sb0 for p half)
            int o = tid & 63, p = tid >> 6;
            const float* srow = sw0 + o * 128 + (z ? 64 : 0) + p * 16;
            float s = 0.f;
#pragma unroll
            for (int i = 0; i < 16; ++i) s += srow[i] * sm.l12.off2[p * 16 + i];
            sm.l12.bp[p][o] = s;
        }
        __syncthreads();
        if (tid < 64)
            sm.l12.bias[tid] = sm.l12.bp[0][tid] + sm.l12.bp[1][tid]
                             + sm.l12.bp[2][tid] + sm.l12.bp[3][tid]
                             + (z == 0 ? sb0[tid] : 0.f);
        __syncthreads();
        const int tx = tid & 7, ty = tid >> 3;
        float4 a0 = {0, 0, 0, 0}, a1 = {0, 0, 0, 0};
        for (int c = 0; c < 128; ++c) {
            float4 hv = *(const float4*)&sm.l12.hl[c][tx * 4];
            float w0 = sm.l12.wl[ty * 2][c], w1v = sm.l12.wl[ty * 2 + 1][c];
            a0.x += w0 * hv.x; a0.y += w0 * hv.y; a0.z += w0 * hv.z; a0.w += w0 * hv.w;
            a1.x += w1v * hv.x; a1.y += w1v * hv.y; a1.z += w1v * hv.z; a1.w += w1v * hv.w;
        }
        float* dst = (z == 0) ? pp : qq;
#pragma unroll
        for (int a = 0; a < 2; ++a) {
            int o = ty * 2 + a;
            float bb = sm.l12.bias[o];
            float4 r = a ? a1 : a0;
            r.x += bb; r.y += bb; r.z += bb; r.w += bb;
            *(float4*)&dst[((size_t)(b * 64 + o)) * NN + n0 + tx * 4] = r;
        }
    }
    gbar(sync, 2);

    // ================= PHASE 4: out[b,i,j] = sb1 + sum_c sw1[c]*relu(pp[c,j]+qq[c,i]) =====
    {
        const int b = blk / 144, rem = blk % 144;
        const int i0 = (rem / 12) * 64, j0 = (rem % 12) * 64;
        // 64 c-rows x 16 float4 per array, BOTH arrays staged per iteration -> 1024 iters
        for (int idx = tid; idx < 1024; idx += 256) {
            int c = idx >> 4, k4 = (idx & 15) * 4;
            *(float4*)&sm.f.pl[c][k4] = *(const float4*)&pp[((size_t)(b * 64 + c)) * NN + j0 + k4];
            *(float4*)&sm.f.ql[c][k4] = *(const float4*)&qq[((size_t)(b * 64 + c)) * NN + i0 + k4];
        }
        if (tid < 64) sm.f.wv[tid] = sw1[tid];
        if (tid == 0) sm.f.sb = sb1[0];
        __syncthreads();
        const int tx = tid & 15, ty = tid >> 4;   // tx: j/4, ty: 4 i rows each
        float sb = sm.f.sb;
        float4 acc[4];
#pragma unroll
        for (int a = 0; a < 4; ++a) acc[a] = make_float4(sb, sb, sb, sb);
#pragma unroll 4
        for (int c = 0; c < 64; ++c) {
            float4 pv = *(const float4*)&sm.f.pl[c][tx * 4];
            float w = sm.f.wv[c];
#pragma unroll
            for (int a = 0; a < 4; ++a) {
                float qv = sm.f.ql[c][ty * 4 + a];
                acc[a].x += w * fmaxf(pv.x + qv, 0.f);
                acc[a].y += w * fmaxf(pv.y + qv, 0.f);
                acc[a].z += w * fmaxf(pv.z + qv, 0.f);
                acc[a].w += w * fmaxf(pv.w + qv, 0.f);
            }
        }
#pragma unroll
        for (int a = 0; a < 4; ++a) {
            size_t base = (size_t)b * NN * NN + (size_t)(i0 + ty * 4 + a) * NN + j0 + tx * 4;
            *(float4*)&out[base] = acc[a];
        }
    }
}

extern "C" void kernel_launch(void* const* d_in, const int* in_sizes, int n_in,
                              void* d_out, int out_size, void* d_ws, size_t ws_size,
                              hipStream_t stream)
{
    const float* x    = (const float*)d_in[0];
    const float* w1_0 = (const float*)d_in[1];
    const float* b1_0 = (const float*)d_in[2];
    const float* w2_0 = (const float*)d_in[3];
    const float* b2_0 = (const float*)d_in[4];
    const float* w1_1 = (const float*)d_in[5];
    const float* b1_1 = (const float*)d_in[6];
    const float* w2_1 = (const float*)d_in[7];
    const float* b2_1 = (const float*)d_in[8];
    const float* w1_2 = (const float*)d_in[9];
    const float* b1_2 = (const float*)d_in[10];
    const float* w2_2 = (const float*)d_in[11];
    const float* b2_2 = (const float*)d_in[12];
    const float* sw0  = (const float*)d_in[13];
    const float* sb0  = (const float*)d_in[14];
    const float* sw1  = (const float*)d_in[15];
    const float* sb1  = (const float*)d_in[16];

    float* ws = (float*)d_ws;

    // zero the 3 barrier counter/flag slots (24 uints)
    (void)hipMemsetAsync(ws + CTR_OFF, 0, 24 * sizeof(unsigned), stream);

    k_mega<<<dim3(NBLK), 256, 0, stream>>>(
        x, w1_0, b1_0, w2_0, b2_0, w1_1, b1_1, w2_1, b2_1,
        w1_2, b1_2, w2_2, b2_2, sw0, sb0, sw1, sb1,
        ws, (float*)d_out);
}

// Round 6
// 83.624 us; speedup vs baseline: 2.1072x; 2.1072x over previous
//
#include <hip/hip_runtime.h>

#define BB 2
#define NN 768
#define FIN 10
#define NBLK 288

// workspace layout (float offsets)
#define WPQ_OFF 0                           // 128*128
#define S1P_OFF 16384                       // B*24*128
#define S2P_OFF (S1P_OFF + BB*24*128)       // B*24*128
#define CTR_OFF (S2P_OFF + BB*24*128)       // 24 uints (3 barriers x 8)
#define H1_OFF  32768                       // B*128*768
#define H2_OFF  (H1_OFF + BB*128*NN)
#define PP_OFF  (H2_OFF + BB*128*NN)        // B*64*768
#define QQ_OFF  (PP_OFF + BB*64*NN)

struct SM_L0 {
    float xt[FIN][36];
    float wl[FIN][128];
    float mu[FIN];
    float offs[128];
    float wred[4][FIN];
    float cred[128][9];
};
struct SM_L12 {
    float hl[128][36];
    float wl[64][132];
    float mul[128];
    float offp[4][64];
    float offs[64];
    float off2[64];
    float bp[4][64];
    float bias[64];
    float cred[64][9];
};
struct SM_WPQ {
    float w2l[64][132];
    float sl[16][68];
};
struct SM_FIN {
    float pl[64][68];
    float ql[64][68];
    float wv[64];
    float sb;
};
union alignas(16) SMem { SM_L0 l0; SM_L12 l12; SM_WPQ w; SM_FIN f; };

// Device-wide barrier, fence-once pattern:
//   arrive = release-fence + RELAXED fetch_add (no per-op cache maintenance)
//   wait   = RELAXED polls (no invalidate per poll!) + s_sleep backoff
//   exit   = single acquire-fence (one invalidate after flag observed)
// Round-5 version polled with ACQUIRE -> cache-invalidate storm from ~240
// spinning blocks = ~55us per barrier. Relaxed polls keep the fabric quiet.
__device__ __forceinline__ void gbar(unsigned* sync, int which)
{
    __syncthreads();
    if (threadIdx.x == 0) {
        __builtin_amdgcn_fence(__ATOMIC_RELEASE, "agent");     // write back prior stores
        unsigned pos = __hip_atomic_fetch_add(&sync[which * 8], 1u,
                            __ATOMIC_RELAXED, __HIP_MEMORY_SCOPE_AGENT);
        if (pos == (unsigned)(NBLK - 1)) {
            __hip_atomic_store(&sync[which * 8 + 4], 1u, __ATOMIC_RELAXED,
                               __HIP_MEMORY_SCOPE_AGENT);
        } else {
            while (__hip_atomic_load(&sync[which * 8 + 4], __ATOMIC_RELAXED,
                                     __HIP_MEMORY_SCOPE_AGENT) == 0u)
                __builtin_amdgcn_s_sleep(8);
        }
        __builtin_amdgcn_fence(__ATOMIC_ACQUIRE, "agent");     // invalidate stale lines once
    }
    __syncthreads();
}

__global__ __launch_bounds__(256) void k_mega(
    const float* __restrict__ x,
    const float* __restrict__ w1_0, const float* __restrict__ b1_0,
    const float* __restrict__ w2_0, const float* __restrict__ b2_0,
    const float* __restrict__ w1_1, const float* __restrict__ b1_1,
    const float* __restrict__ w2_1, const float* __restrict__ b2_1,
    const float* __restrict__ w1_2, const float* __restrict__ b1_2,
    const float* __restrict__ w2_2, const float* __restrict__ b2_2,
    const float* __restrict__ sw0, const float* __restrict__ sb0,
    const float* __restrict__ sw1, const float* __restrict__ sb1,
    float* ws, float* __restrict__ out)
{
    __shared__ SMem sm;
    const int blk = blockIdx.x, tid = threadIdx.x;

    float* wpq = ws + WPQ_OFF;
    float* s1p = ws + S1P_OFF;
    float* s2p = ws + S2P_OFF;
    float* h1  = ws + H1_OFF;
    float* h2  = ws + H2_OFF;
    float* pp  = ws + PP_OFF;
    float* qq  = ws + QQ_OFF;
    unsigned* sync = (unsigned*)(ws + CTR_OFF);

    // ================= PHASE 1 =================
    if (blk < 48) {
        // layer0: b in {0,1}, 24 n-tiles of 32; out h1[128o][32n], colsum partial -> s1p
        const int b = blk / 24, nt = blk % 24, n0 = nt * 32;
        for (int idx = tid; idx < FIN * 32; idx += 256) {
            int n = idx / FIN, c = idx % FIN;
            sm.l0.xt[c][n] = x[(b * NN + n0 + n) * FIN + c];
        }
        for (int idx = tid; idx < FIN * 128; idx += 256) {
            int o = idx / FIN, c = idx % FIN;
            sm.l0.wl[c][o] = w1_0[o * FIN + c] + w2_0[o * FIN + c];
        }
        // x-mean (redundant per block; x is 30KB, L2-hot)
        float part[FIN];
#pragma unroll
        for (int c = 0; c < FIN; ++c) part[c] = 0.f;
        for (int n = tid; n < NN; n += 256) {
            const float* xp = x + (b * NN + n) * FIN;
#pragma unroll
            for (int c = 0; c < FIN; ++c) part[c] += xp[c];
        }
#pragma unroll
        for (int off = 32; off > 0; off >>= 1) {
#pragma unroll
            for (int c = 0; c < FIN; ++c) part[c] += __shfl_down(part[c], off);
        }
        if ((tid & 63) == 0) {
#pragma unroll
            for (int c = 0; c < FIN; ++c) sm.l0.wred[tid >> 6][c] = part[c];
        }
        __syncthreads();
        if (tid < FIN) {
            float s = sm.l0.wred[0][tid] + sm.l0.wred[1][tid]
                    + sm.l0.wred[2][tid] + sm.l0.wred[3][tid];
            sm.l0.mu[tid] = s * (1.f / (float)NN);
        }
        __syncthreads();
        if (tid < 128) {
            float o = b1_0[tid] + b2_0[tid];
#pragma unroll
            for (int c = 0; c < FIN; ++c) o -= w2_0[tid * FIN + c] * sm.l0.mu[c];
            sm.l0.offs[tid] = o;
        }
        __syncthreads();
        const int tx = tid & 7, ty = tid >> 3;     // tx: n/4, ty: 4 o rows each
        float4 acc[4];
#pragma unroll
        for (int a = 0; a < 4; ++a) {
            float o = sm.l0.offs[ty * 4 + a];
            acc[a] = make_float4(o, o, o, o);
        }
#pragma unroll
        for (int c = 0; c < FIN; ++c) {
            float4 xv = *(const float4*)&sm.l0.xt[c][tx * 4];
#pragma unroll
            for (int a = 0; a < 4; ++a) {
                float w = sm.l0.wl[c][ty * 4 + a];
                acc[a].x += w * xv.x; acc[a].y += w * xv.y;
                acc[a].z += w * xv.z; acc[a].w += w * xv.w;
            }
        }
#pragma unroll
        for (int a = 0; a < 4; ++a) {
            int o = ty * 4 + a;
            float4 r = acc[a];
            r.x = fmaxf(r.x, 0.f); r.y = fmaxf(r.y, 0.f);
            r.z = fmaxf(r.z, 0.f); r.w = fmaxf(r.w, 0.f);
            *(float4*)&h1[((size_t)(b * 128 + o)) * NN + n0 + tx * 4] = r;
            sm.l0.cred[o][tx] = r.x + r.y + r.z + r.w;
        }
        __syncthreads();
        if (tid < 128) {
            float s = 0.f;
#pragma unroll
            for (int t = 0; t < 8; ++t) s += sm.l0.cred[tid][t];
            s1p[(b * 24 + nt) * 128 + tid] = s;
        }
    } else if (blk >= 280) {
        // Wpq[o][c] = sum_k S[o][k]*(w1_2[k][c]+w2_2[k][c]); 8 blocks x 16 rows
        const int o0 = (blk - 280) * 16;
        for (int idx = tid; idx < 2048; idx += 256) {
            int k = idx >> 5, c4 = (idx & 31) * 4;
            float4 a = *(const float4*)&w1_2[k * 128 + c4];
            float4 b = *(const float4*)&w2_2[k * 128 + c4];
            float4 r = {a.x + b.x, a.y + b.y, a.z + b.z, a.w + b.w};
            *(float4*)&sm.w.w2l[k][c4] = r;
        }
        for (int idx = tid; idx < 16 * 64; idx += 256) {
            int o = idx >> 6, k = idx & 63;
            int oo = o0 + o;
            sm.w.sl[o][k] = (oo < 64) ? sw0[oo * 128 + k] : sw0[(oo - 64) * 128 + 64 + k];
        }
        __syncthreads();
        const int tx = tid & 31, ty = tid >> 5;   // 2 o rows each
        float4 a0 = {0, 0, 0, 0}, a1 = {0, 0, 0, 0};
        for (int k = 0; k < 64; ++k) {
            float4 wv = *(const float4*)&sm.w.w2l[k][tx * 4];
            float s0 = sm.w.sl[ty * 2][k], s1v = sm.w.sl[ty * 2 + 1][k];
            a0.x += s0 * wv.x; a0.y += s0 * wv.y; a0.z += s0 * wv.z; a0.w += s0 * wv.w;
            a1.x += s1v * wv.x; a1.y += s1v * wv.y; a1.z += s1v * wv.z; a1.w += s1v * wv.w;
        }
        *(float4*)&wpq[(o0 + ty * 2) * 128 + tx * 4] = a0;
        *(float4*)&wpq[(o0 + ty * 2 + 1) * 128 + tx * 4] = a1;
    }
    gbar(sync, 0);

    // ================= PHASE 2: layer1 =================
    if (blk < 96) {
        const int b = blk & 1, z = (blk >> 1) & 1, nt = blk >> 2;
        const int n0 = nt * 32, o0 = z * 64;
        if (tid < 128) {
            float s = 0.f;
#pragma unroll
            for (int k = 0; k < 24; ++k) s += s1p[(b * 24 + k) * 128 + tid];
            sm.l12.mul[tid] = s * (1.f / (float)NN);
        }
        for (int idx = tid; idx < 1024; idx += 256) {
            int c = idx >> 3, n4 = (idx & 7) * 4;
            *(float4*)&sm.l12.hl[c][n4] = *(const float4*)&h1[((size_t)(b * 128 + c)) * NN + n0 + n4];
        }
        for (int idx = tid; idx < 2048; idx += 256) {
            int o = idx >> 5, c4 = (idx & 31) * 4;
            float4 a = *(const float4*)&w1_1[(o0 + o) * 128 + c4];
            float4 bb = *(const float4*)&w2_1[(o0 + o) * 128 + c4];
            float4 r = {a.x + bb.x, a.y + bb.y, a.z + bb.z, a.w + bb.w};
            *(float4*)&sm.l12.wl[o][c4] = r;
        }
        __syncthreads();
        {
            int o = tid & 63, p = tid >> 6;
            const float* w2r = w2_1 + (o0 + o) * 128 + p * 32;
            const float* mr = sm.l12.mul + p * 32;
            float s = 0.f;
#pragma unroll
            for (int i = 0; i < 32; ++i) s += w2r[i] * mr[i];
            sm.l12.offp[p][o] = s;
        }
        __syncthreads();
        if (tid < 64)
            sm.l12.offs[tid] = b1_1[o0 + tid] + b2_1[o0 + tid]
                             - sm.l12.offp[0][tid] - sm.l12.offp[1][tid]
                             - sm.l12.offp[2][tid] - sm.l12.offp[3][tid];
        __syncthreads();
        const int tx = tid & 7, ty = tid >> 3;     // 2 o rows, 4 n each
        float4 a0 = {0, 0, 0, 0}, a1 = {0, 0, 0, 0};
        for (int c = 0; c < 128; ++c) {
            float4 hv = *(const float4*)&sm.l12.hl[c][tx * 4];
            float w0 = sm.l12.wl[ty * 2][c], w1v = sm.l12.wl[ty * 2 + 1][c];
            a0.x += w0 * hv.x; a0.y += w0 * hv.y; a0.z += w0 * hv.z; a0.w += w0 * hv.w;
            a1.x += w1v * hv.x; a1.y += w1v * hv.y; a1.z += w1v * hv.z; a1.w += w1v * hv.w;
        }
#pragma unroll
        for (int a = 0; a < 2; ++a) {
            int o = ty * 2 + a;
            float off = sm.l12.offs[o];
            float4 r = a ? a1 : a0;
            r.x = fmaxf(r.x + off, 0.f); r.y = fmaxf(r.y + off, 0.f);
            r.z = fmaxf(r.z + off, 0.f); r.w = fmaxf(r.w + off, 0.f);
            *(float4*)&h2[((size_t)(b * 128 + o0 + o)) * NN + n0 + tx * 4] = r;
            sm.l12.cred[o][tx] = r.x + r.y + r.z + r.w;
        }
        __syncthreads();
        if (tid < 64) {
            float s = 0.f;
#pragma unroll
            for (int t = 0; t < 8; ++t) s += sm.l12.cred[tid][t];
            s2p[(b * 24 + nt) * 128 + o0 + tid] = s;
        }
    }
    gbar(sync, 1);

    // ================= PHASE 3: pp/qq = Wpq @ h2 + bias =================
    if (blk < 96) {
        const int b = blk & 1, z = (blk >> 1) & 1, nt = blk >> 2;
        const int n0 = nt * 32, o0 = z * 64;
        if (tid < 128) {
            float s = 0.f;
#pragma unroll
            for (int k = 0; k < 24; ++k) s += s2p[(b * 24 + k) * 128 + tid];
            sm.l12.mul[tid] = s * (1.f / (float)NN);
        }
        for (int idx = tid; idx < 1024; idx += 256) {
            int c = idx >> 3, n4 = (idx & 7) * 4;
            *(float4*)&sm.l12.hl[c][n4] = *(const float4*)&h2[((size_t)(b * 128 + c)) * NN + n0 + n4];
        }
        for (int idx = tid; idx < 2048; idx += 256) {
            int o = idx >> 5, c4 = (idx & 31) * 4;
            *(float4*)&sm.l12.wl[o][c4] = *(const float4*)&wpq[(o0 + o) * 128 + c4];
        }
        __syncthreads();
        {   // off2[k] = b1_2+b2_2 - w2_2 @ mul  (u-channel offsets)
            int k = tid & 63, p = tid >> 6;
            const float* w2r = w2_2 + k * 128 + p * 32;
            const float* mr = sm.l12.mul + p * 32;
            float s = 0.f;
#pragma unroll
            for (int i = 0; i < 32; ++i) s += w2r[i] * mr[i];
            sm.l12.offp[p][k] = s;
        }
        __syncthreads();
        if (tid < 64)
            sm.l12.off2[tid] = b1_2[tid] + b2_2[tid]
                             - sm.l12.offp[0][tid] - sm.l12.offp[1][tid]
                             - sm.l12.offp[2][tid] - sm.l12.offp[3][tid];
        __syncthreads();
        {   // bias[o] = S[o] @ off2 (+ sb0 for p half)
            int o = tid & 63, p = tid >> 6;
            const float* srow = sw0 + o * 128 + (z ? 64 : 0) + p * 16;
            float s = 0.f;
#pragma unroll
            for (int i = 0; i < 16; ++i) s += srow[i] * sm.l12.off2[p * 16 + i];
            sm.l12.bp[p][o] = s;
        }
        __syncthreads();
        if (tid < 64)
            sm.l12.bias[tid] = sm.l12.bp[0][tid] + sm.l12.bp[1][tid]
                             + sm.l12.bp[2][tid] + sm.l12.bp[3][tid]
                             + (z == 0 ? sb0[tid] : 0.f);
        __syncthreads();
        const int tx = tid & 7, ty = tid >> 3;
        float4 a0 = {0, 0, 0, 0}, a1 = {0, 0, 0, 0};
        for (int c = 0; c < 128; ++c) {
            float4 hv = *(const float4*)&sm.l12.hl[c][tx * 4];
            float w0 = sm.l12.wl[ty * 2][c], w1v = sm.l12.wl[ty * 2 + 1][c];
            a0.x += w0 * hv.x; a0.y += w0 * hv.y; a0.z += w0 * hv.z; a0.w += w0 * hv.w;
            a1.x += w1v * hv.x; a1.y += w1v * hv.y; a1.z += w1v * hv.z; a1.w += w1v * hv.w;
        }
        float* dst = (z == 0) ? pp : qq;
#pragma unroll
        for (int a = 0; a < 2; ++a) {
            int o = ty * 2 + a;
            float bb = sm.l12.bias[o];
            float4 r = a ? a1 : a0;
            r.x += bb; r.y += bb; r.z += bb; r.w += bb;
            *(float4*)&dst[((size_t)(b * 64 + o)) * NN + n0 + tx * 4] = r;
        }
    }
    gbar(sync, 2);

    // ================= PHASE 4: out[b,i,j] = sb1 + sum_c sw1[c]*relu(pp[c,j]+qq[c,i]) =====
    {
        const int b = blk / 144, rem = blk % 144;
        const int i0 = (rem / 12) * 64, j0 = (rem % 12) * 64;
        // 64 c-rows x 16 float4 per array, BOTH arrays staged per iteration -> 1024 iters
        for (int idx = tid; idx < 1024; idx += 256) {
            int c = idx >> 4, k4 = (idx & 15) * 4;
            *(float4*)&sm.f.pl[c][k4] = *(const float4*)&pp[((size_t)(b * 64 + c)) * NN + j0 + k4];
            *(float4*)&sm.f.ql[c][k4] = *(const float4*)&qq[((size_t)(b * 64 + c)) * NN + i0 + k4];
        }
        if (tid < 64) sm.f.wv[tid] = sw1[tid];
        if (tid == 0) sm.f.sb = sb1[0];
        __syncthreads();
        const int tx = tid & 15, ty = tid >> 4;   // tx: j/4, ty: 4 i rows each
        float sb = sm.f.sb;
        float4 acc[4];
#pragma unroll
        for (int a = 0; a < 4; ++a) acc[a] = make_float4(sb, sb, sb, sb);
#pragma unroll 4
        for (int c = 0; c < 64; ++c) {
            float4 pv = *(const float4*)&sm.f.pl[c][tx * 4];
            float w = sm.f.wv[c];
#pragma unroll
            for (int a = 0; a < 4; ++a) {
                float qv = sm.f.ql[c][ty * 4 + a];
                acc[a].x += w * fmaxf(pv.x + qv, 0.f);
                acc[a].y += w * fmaxf(pv.y + qv, 0.f);
                acc[a].z += w * fmaxf(pv.z + qv, 0.f);
                acc[a].w += w * fmaxf(pv.w + qv, 0.f);
            }
        }
#pragma unroll
        for (int a = 0; a < 4; ++a) {
            size_t base = (size_t)b * NN * NN + (size_t)(i0 + ty * 4 + a) * NN + j0 + tx * 4;
            *(float4*)&out[base] = acc[a];
        }
    }
}

extern "C" void kernel_launch(void* const* d_in, const int* in_sizes, int n_in,
                              void* d_out, int out_size, void* d_ws, size_t ws_size,
                              hipStream_t stream)
{
    const float* x    = (const float*)d_in[0];
    const float* w1_0 = (const float*)d_in[1];
    const float* b1_0 = (const float*)d_in[2];
    const float* w2_0 = (const float*)d_in[3];
    const float* b2_0 = (const float*)d_in[4];
    const float* w1_1 = (const float*)d_in[5];
    const float* b1_1 = (const float*)d_in[6];
    const float* w2_1 = (const float*)d_in[7];
    const float* b2_1 = (const float*)d_in[8];
    const float* w1_2 = (const float*)d_in[9];
    const float* b1_2 = (const float*)d_in[10];
    const float* w2_2 = (const float*)d_in[11];
    const float* b2_2 = (const float*)d_in[12];
    const float* sw0  = (const float*)d_in[13];
    const float* sb0  = (const float*)d_in[14];
    const float* sw1  = (const float*)d_in[15];
    const float* sb1  = (const float*)d_in[16];

    float* ws = (float*)d_ws;

    // zero the 3 barrier counter/flag slots (24 uints)
    (void)hipMemsetAsync(ws + CTR_OFF, 0, 24 * sizeof(unsigned), stream);

    k_mega<<<dim3(NBLK), 256, 0, stream>>>(
        x, w1_0, b1_0, w2_0, b2_0, w1_1, b1_1, w2_1, b2_1,
        w1_2, b1_2, w2_2, b2_2, sw0, sb0, sw1, sb1,
        ws, (float*)d_out);
}

// Round 7
// 64.546 us; speedup vs baseline: 2.7300x; 1.2956x over previous
//
#include <hip/hip_runtime.h>

#define BB 2
#define NN 768
#define FIN 10
#define NBLK 288

// workspace layout (float offsets)
#define WPQ_OFF 0                           // 128*128
#define S1P_OFF 16384                       // B*24*128
#define S2P_OFF (S1P_OFF + BB*24*128)       // B*24*128
#define CTR_OFF (S2P_OFF + BB*24*128)       // 32 + NBLK*16 uints (ctrs + per-block flags)
#define H1_OFF  36864                       // B*128*768
#define H2_OFF  (H1_OFF + BB*128*NN)
#define PP_OFF  (H2_OFF + BB*128*NN)        // B*64*768
#define QQ_OFF  (PP_OFF + BB*64*NN)
#define SYNC_DWORDS (32 + NBLK*16)

struct SM_L0 {
    float xt[FIN][36];
    float wl[FIN][128];
    float mu[FIN];
    float offs[128];
    float wred[4][FIN];
    float cred[128][9];
};
struct SM_L12 {
    float hl[128][36];
    float wl[64][132];
    float mul[128];
    float offp[4][64];
    float offs[64];
    float off2[64];
    float bp[4][64];
    float bias[64];
    float cred[64][9];
};
struct SM_WPQ {
    float w2l[64][132];
    float sl[16][68];
};
struct SM_FIN {
    float pl[64][68];
    float ql[64][68];
    float wv[64];
    float sb;
};
union alignas(16) SMem { SM_L0 l0; SM_L12 l12; SM_WPQ w; SM_FIN f; };

// Device-wide barrier, fence-once + REPLICATED FLAGS.
// R6 lesson: one shared flag dword polled by ~287 leaders = single-L2-bank
// queue saturation (~20us/barrier). Now: counters at sync[which*8]; flag for
// (blk,which) at sync[32 + blk*16 + which*4] (64B per block, spread across
// L2 channels). Last arriver broadcast-stores NBLK flags; each leader polls
// only ITS OWN line -> no hot bank.
__device__ __forceinline__ void gbar(unsigned* sync, int which, int blk)
{
    __syncthreads();
    if (threadIdx.x == 0) {
        __builtin_amdgcn_fence(__ATOMIC_RELEASE, "agent");     // write back prior stores
        unsigned pos = __hip_atomic_fetch_add(&sync[which * 8], 1u,
                            __ATOMIC_RELAXED, __HIP_MEMORY_SCOPE_AGENT);
        unsigned* flags = sync + 32;
        if (pos == (unsigned)(NBLK - 1)) {
            for (int i = 0; i < NBLK; ++i)
                __hip_atomic_store(&flags[i * 16 + which * 4], 1u,
                                   __ATOMIC_RELAXED, __HIP_MEMORY_SCOPE_AGENT);
        } else {
            while (__hip_atomic_load(&flags[blk * 16 + which * 4],
                                     __ATOMIC_RELAXED, __HIP_MEMORY_SCOPE_AGENT) == 0u)
                __builtin_amdgcn_s_sleep(2);
        }
        __builtin_amdgcn_fence(__ATOMIC_ACQUIRE, "agent");     // invalidate stale lines once
    }
    __syncthreads();
}

__global__ __launch_bounds__(256) void k_mega(
    const float* __restrict__ x,
    const float* __restrict__ w1_0, const float* __restrict__ b1_0,
    const float* __restrict__ w2_0, const float* __restrict__ b2_0,
    const float* __restrict__ w1_1, const float* __restrict__ b1_1,
    const float* __restrict__ w2_1, const float* __restrict__ b2_1,
    const float* __restrict__ w1_2, const float* __restrict__ b1_2,
    const float* __restrict__ w2_2, const float* __restrict__ b2_2,
    const float* __restrict__ sw0, const float* __restrict__ sb0,
    const float* __restrict__ sw1, const float* __restrict__ sb1,
    float* ws, float* __restrict__ out)
{
    __shared__ SMem sm;
    const int blk = blockIdx.x, tid = threadIdx.x;

    float* wpq = ws + WPQ_OFF;
    float* s1p = ws + S1P_OFF;
    float* s2p = ws + S2P_OFF;
    float* h1  = ws + H1_OFF;
    float* h2  = ws + H2_OFF;
    float* pp  = ws + PP_OFF;
    float* qq  = ws + QQ_OFF;
    unsigned* sync = (unsigned*)(ws + CTR_OFF);

    // ================= PHASE 1 =================
    if (blk < 48) {
        // layer0: b in {0,1}, 24 n-tiles of 32; out h1[128o][32n], colsum partial -> s1p
        const int b = blk / 24, nt = blk % 24, n0 = nt * 32;
        for (int idx = tid; idx < FIN * 32; idx += 256) {
            int n = idx / FIN, c = idx % FIN;
            sm.l0.xt[c][n] = x[(b * NN + n0 + n) * FIN + c];
        }
        for (int idx = tid; idx < FIN * 128; idx += 256) {
            int o = idx / FIN, c = idx % FIN;
            sm.l0.wl[c][o] = w1_0[o * FIN + c] + w2_0[o * FIN + c];
        }
        // x-mean (redundant per block; x is 30KB, L2-hot)
        float part[FIN];
#pragma unroll
        for (int c = 0; c < FIN; ++c) part[c] = 0.f;
        for (int n = tid; n < NN; n += 256) {
            const float* xp = x + (b * NN + n) * FIN;
#pragma unroll
            for (int c = 0; c < FIN; ++c) part[c] += xp[c];
        }
#pragma unroll
        for (int off = 32; off > 0; off >>= 1) {
#pragma unroll
            for (int c = 0; c < FIN; ++c) part[c] += __shfl_down(part[c], off);
        }
        if ((tid & 63) == 0) {
#pragma unroll
            for (int c = 0; c < FIN; ++c) sm.l0.wred[tid >> 6][c] = part[c];
        }
        __syncthreads();
        if (tid < FIN) {
            float s = sm.l0.wred[0][tid] + sm.l0.wred[1][tid]
                    + sm.l0.wred[2][tid] + sm.l0.wred[3][tid];
            sm.l0.mu[tid] = s * (1.f / (float)NN);
        }
        __syncthreads();
        if (tid < 128) {
            float o = b1_0[tid] + b2_0[tid];
#pragma unroll
            for (int c = 0; c < FIN; ++c) o -= w2_0[tid * FIN + c] * sm.l0.mu[c];
            sm.l0.offs[tid] = o;
        }
        __syncthreads();
        const int tx = tid & 7, ty = tid >> 3;     // tx: n/4, ty: 4 o rows each
        float4 acc[4];
#pragma unroll
        for (int a = 0; a < 4; ++a) {
            float o = sm.l0.offs[ty * 4 + a];
            acc[a] = make_float4(o, o, o, o);
        }
#pragma unroll
        for (int c = 0; c < FIN; ++c) {
            float4 xv = *(const float4*)&sm.l0.xt[c][tx * 4];
#pragma unroll
            for (int a = 0; a < 4; ++a) {
                float w = sm.l0.wl[c][ty * 4 + a];
                acc[a].x += w * xv.x; acc[a].y += w * xv.y;
                acc[a].z += w * xv.z; acc[a].w += w * xv.w;
            }
        }
#pragma unroll
        for (int a = 0; a < 4; ++a) {
            int o = ty * 4 + a;
            float4 r = acc[a];
            r.x = fmaxf(r.x, 0.f); r.y = fmaxf(r.y, 0.f);
            r.z = fmaxf(r.z, 0.f); r.w = fmaxf(r.w, 0.f);
            *(float4*)&h1[((size_t)(b * 128 + o)) * NN + n0 + tx * 4] = r;
            sm.l0.cred[o][tx] = r.x + r.y + r.z + r.w;
        }
        __syncthreads();
        if (tid < 128) {
            float s = 0.f;
#pragma unroll
            for (int t = 0; t < 8; ++t) s += sm.l0.cred[tid][t];
            s1p[(b * 24 + nt) * 128 + tid] = s;
        }
    } else if (blk >= 280) {
        // Wpq[o][c] = sum_k S[o][k]*(w1_2[k][c]+w2_2[k][c]); 8 blocks x 16 rows
        const int o0 = (blk - 280) * 16;
        for (int idx = tid; idx < 2048; idx += 256) {
            int k = idx >> 5, c4 = (idx & 31) * 4;
            float4 a = *(const float4*)&w1_2[k * 128 + c4];
            float4 b = *(const float4*)&w2_2[k * 128 + c4];
            float4 r = {a.x + b.x, a.y + b.y, a.z + b.z, a.w + b.w};
            *(float4*)&sm.w.w2l[k][c4] = r;
        }
        for (int idx = tid; idx < 16 * 64; idx += 256) {
            int o = idx >> 6, k = idx & 63;
            int oo = o0 + o;
            sm.w.sl[o][k] = (oo < 64) ? sw0[oo * 128 + k] : sw0[(oo - 64) * 128 + 64 + k];
        }
        __syncthreads();
        const int tx = tid & 31, ty = tid >> 5;   // 2 o rows each
        float4 a0 = {0, 0, 0, 0}, a1 = {0, 0, 0, 0};
        for (int k = 0; k < 64; ++k) {
            float4 wv = *(const float4*)&sm.w.w2l[k][tx * 4];
            float s0 = sm.w.sl[ty * 2][k], s1v = sm.w.sl[ty * 2 + 1][k];
            a0.x += s0 * wv.x; a0.y += s0 * wv.y; a0.z += s0 * wv.z; a0.w += s0 * wv.w;
            a1.x += s1v * wv.x; a1.y += s1v * wv.y; a1.z += s1v * wv.z; a1.w += s1v * wv.w;
        }
        *(float4*)&wpq[(o0 + ty * 2) * 128 + tx * 4] = a0;
        *(float4*)&wpq[(o0 + ty * 2 + 1) * 128 + tx * 4] = a1;
    }
    gbar(sync, 0, blk);

    // ================= PHASE 2: layer1 =================
    if (blk < 96) {
        const int b = blk & 1, z = (blk >> 1) & 1, nt = blk >> 2;
        const int n0 = nt * 32, o0 = z * 64;
        if (tid < 128) {
            float s = 0.f;
#pragma unroll
            for (int k = 0; k < 24; ++k) s += s1p[(b * 24 + k) * 128 + tid];
            sm.l12.mul[tid] = s * (1.f / (float)NN);
        }
        for (int idx = tid; idx < 1024; idx += 256) {
            int c = idx >> 3, n4 = (idx & 7) * 4;
            *(float4*)&sm.l12.hl[c][n4] = *(const float4*)&h1[((size_t)(b * 128 + c)) * NN + n0 + n4];
        }
        for (int idx = tid; idx < 2048; idx += 256) {
            int o = idx >> 5, c4 = (idx & 31) * 4;
            float4 a = *(const float4*)&w1_1[(o0 + o) * 128 + c4];
            float4 bb = *(const float4*)&w2_1[(o0 + o) * 128 + c4];
            float4 r = {a.x + bb.x, a.y + bb.y, a.z + bb.z, a.w + bb.w};
            *(float4*)&sm.l12.wl[o][c4] = r;
        }
        __syncthreads();
        {
            int o = tid & 63, p = tid >> 6;
            const float* w2r = w2_1 + (o0 + o) * 128 + p * 32;
            const float* mr = sm.l12.mul + p * 32;
            float s = 0.f;
#pragma unroll
            for (int i = 0; i < 32; ++i) s += w2r[i] * mr[i];
            sm.l12.offp[p][o] = s;
        }
        __syncthreads();
        if (tid < 64)
            sm.l12.offs[tid] = b1_1[o0 + tid] + b2_1[o0 + tid]
                             - sm.l12.offp[0][tid] - sm.l12.offp[1][tid]
                             - sm.l12.offp[2][tid] - sm.l12.offp[3][tid];
        __syncthreads();
        const int tx = tid & 7, ty = tid >> 3;     // 2 o rows, 4 n each
        float4 a0 = {0, 0, 0, 0}, a1 = {0, 0, 0, 0};
        for (int c = 0; c < 128; ++c) {
            float4 hv = *(const float4*)&sm.l12.hl[c][tx * 4];
            float w0 = sm.l12.wl[ty * 2][c], w1v = sm.l12.wl[ty * 2 + 1][c];
            a0.x += w0 * hv.x; a0.y += w0 * hv.y; a0.z += w0 * hv.z; a0.w += w0 * hv.w;
            a1.x += w1v * hv.x; a1.y += w1v * hv.y; a1.z += w1v * hv.z; a1.w += w1v * hv.w;
        }
#pragma unroll
        for (int a = 0; a < 2; ++a) {
            int o = ty * 2 + a;
            float off = sm.l12.offs[o];
            float4 r = a ? a1 : a0;
            r.x = fmaxf(r.x + off, 0.f); r.y = fmaxf(r.y + off, 0.f);
            r.z = fmaxf(r.z + off, 0.f); r.w = fmaxf(r.w + off, 0.f);
            *(float4*)&h2[((size_t)(b * 128 + o0 + o)) * NN + n0 + tx * 4] = r;
            sm.l12.cred[o][tx] = r.x + r.y + r.z + r.w;
        }
        __syncthreads();
        if (tid < 64) {
            float s = 0.f;
#pragma unroll
            for (int t = 0; t < 8; ++t) s += sm.l12.cred[tid][t];
            s2p[(b * 24 + nt) * 128 + o0 + tid] = s;
        }
    }
    gbar(sync, 1, blk);

    // ================= PHASE 3: pp/qq = Wpq @ h2 + bias =================
    if (blk < 96) {
        const int b = blk & 1, z = (blk >> 1) & 1, nt = blk >> 2;
        const int n0 = nt * 32, o0 = z * 64;
        if (tid < 128) {
            float s = 0.f;
#pragma unroll
            for (int k = 0; k < 24; ++k) s += s2p[(b * 24 + k) * 128 + tid];
            sm.l12.mul[tid] = s * (1.f / (float)NN);
        }
        for (int idx = tid; idx < 1024; idx += 256) {
            int c = idx >> 3, n4 = (idx & 7) * 4;
            *(float4*)&sm.l12.hl[c][n4] = *(const float4*)&h2[((size_t)(b * 128 + c)) * NN + n0 + n4];
        }
        for (int idx = tid; idx < 2048; idx += 256) {
            int o = idx >> 5, c4 = (idx & 31) * 4;
            *(float4*)&sm.l12.wl[o][c4] = *(const float4*)&wpq[(o0 + o) * 128 + c4];
        }
        __syncthreads();
        {   // off2[k] = b1_2+b2_2 - w2_2 @ mul  (u-channel offsets)
            int k = tid & 63, p = tid >> 6;
            const float* w2r = w2_2 + k * 128 + p * 32;
            const float* mr = sm.l12.mul + p * 32;
            float s = 0.f;
#pragma unroll
            for (int i = 0; i < 32; ++i) s += w2r[i] * mr[i];
            sm.l12.offp[p][k] = s;
        }
        __syncthreads();
        if (tid < 64)
            sm.l12.off2[tid] = b1_2[tid] + b2_2[tid]
                             - sm.l12.offp[0][tid] - sm.l12.offp[1][tid]
                             - sm.l12.offp[2][tid] - sm.l12.offp[3][tid];
        __syncthreads();
        {   // bias[o] = S[o] @ off2 (+ sb0 for p half)
            int o = tid & 63, p = tid >> 6;
            const float* srow = sw0 + o * 128 + (z ? 64 : 0) + p * 16;
            float s = 0.f;
#pragma unroll
            for (int i = 0; i < 16; ++i) s += srow[i] * sm.l12.off2[p * 16 + i];
            sm.l12.bp[p][o] = s;
        }
        __syncthreads();
        if (tid < 64)
            sm.l12.bias[tid] = sm.l12.bp[0][tid] + sm.l12.bp[1][tid]
                             + sm.l12.bp[2][tid] + sm.l12.bp[3][tid]
                             + (z == 0 ? sb0[tid] : 0.f);
        __syncthreads();
        const int tx = tid & 7, ty = tid >> 3;
        float4 a0 = {0, 0, 0, 0}, a1 = {0, 0, 0, 0};
        for (int c = 0; c < 128; ++c) {
            float4 hv = *(const float4*)&sm.l12.hl[c][tx * 4];
            float w0 = sm.l12.wl[ty * 2][c], w1v = sm.l12.wl[ty * 2 + 1][c];
            a0.x += w0 * hv.x; a0.y += w0 * hv.y; a0.z += w0 * hv.z; a0.w += w0 * hv.w;
            a1.x += w1v * hv.x; a1.y += w1v * hv.y; a1.z += w1v * hv.z; a1.w += w1v * hv.w;
        }
        float* dst = (z == 0) ? pp : qq;
#pragma unroll
        for (int a = 0; a < 2; ++a) {
            int o = ty * 2 + a;
            float bb = sm.l12.bias[o];
            float4 r = a ? a1 : a0;
            r.x += bb; r.y += bb; r.z += bb; r.w += bb;
            *(float4*)&dst[((size_t)(b * 64 + o)) * NN + n0 + tx * 4] = r;
        }
    }
    gbar(sync, 2, blk);

    // ================= PHASE 4: out[b,i,j] = sb1 + sum_c sw1[c]*relu(pp[c,j]+qq[c,i]) =====
    {
        const int b = blk / 144, rem = blk % 144;
        const int i0 = (rem / 12) * 64, j0 = (rem % 12) * 64;
        // 64 c-rows x 16 float4 per array, BOTH arrays staged per iteration -> 1024 iters
        for (int idx = tid; idx < 1024; idx += 256) {
            int c = idx >> 4, k4 = (idx & 15) * 4;
            *(float4*)&sm.f.pl[c][k4] = *(const float4*)&pp[((size_t)(b * 64 + c)) * NN + j0 + k4];
            *(float4*)&sm.f.ql[c][k4] = *(const float4*)&qq[((size_t)(b * 64 + c)) * NN + i0 + k4];
        }
        if (tid < 64) sm.f.wv[tid] = sw1[tid];
        if (tid == 0) sm.f.sb = sb1[0];
        __syncthreads();
        const int tx = tid & 15, ty = tid >> 4;   // tx: j/4, ty: 4 i rows each
        float sb = sm.f.sb;
        float4 acc[4];
#pragma unroll
        for (int a = 0; a < 4; ++a) acc[a] = make_float4(sb, sb, sb, sb);
#pragma unroll 4
        for (int c = 0; c < 64; ++c) {
            float4 pv = *(const float4*)&sm.f.pl[c][tx * 4];
            float w = sm.f.wv[c];
#pragma unroll
            for (int a = 0; a < 4; ++a) {
                float qv = sm.f.ql[c][ty * 4 + a];
                acc[a].x += w * fmaxf(pv.x + qv, 0.f);
                acc[a].y += w * fmaxf(pv.y + qv, 0.f);
                acc[a].z += w * fmaxf(pv.z + qv, 0.f);
                acc[a].w += w * fmaxf(pv.w + qv, 0.f);
            }
        }
#pragma unroll
        for (int a = 0; a < 4; ++a) {
            size_t base = (size_t)b * NN * NN + (size_t)(i0 + ty * 4 + a) * NN + j0 + tx * 4;
            *(float4*)&out[base] = acc[a];
        }
    }
}

extern "C" void kernel_launch(void* const* d_in, const int* in_sizes, int n_in,
                              void* d_out, int out_size, void* d_ws, size_t ws_size,
                              hipStream_t stream)
{
    const float* x    = (const float*)d_in[0];
    const float* w1_0 = (const float*)d_in[1];
    const float* b1_0 = (const float*)d_in[2];
    const float* w2_0 = (const float*)d_in[3];
    const float* b2_0 = (const float*)d_in[4];
    const float* w1_1 = (const float*)d_in[5];
    const float* b1_1 = (const float*)d_in[6];
    const float* w2_1 = (const float*)d_in[7];
    const float* b2_1 = (const float*)d_in[8];
    const float* w1_2 = (const float*)d_in[9];
    const float* b1_2 = (const float*)d_in[10];
    const float* w2_2 = (const float*)d_in[11];
    const float* b2_2 = (const float*)d_in[12];
    const float* sw0  = (const float*)d_in[13];
    const float* sb0  = (const float*)d_in[14];
    const float* sw1  = (const float*)d_in[15];
    const float* sb1  = (const float*)d_in[16];

    float* ws = (float*)d_ws;

    // zero barrier counters + per-block flag lines
    (void)hipMemsetAsync(ws + CTR_OFF, 0, SYNC_DWORDS * sizeof(unsigned), stream);

    k_mega<<<dim3(NBLK), 256, 0, stream>>>(
        x, w1_0, b1_0, w2_0, b2_0, w1_1, b1_1, w2_1, b2_1,
        w1_2, b1_2, w2_2, b2_2, sw0, sb0, sw1, sb1,
        ws, (float*)d_out);
}